// Round 1
// baseline (708.880 us; speedup 1.0000x reference)
//
#include <hip/hip_runtime.h>
#include <hip/hip_bf16.h>
#include <cstdint>

#define DD 256      // input dim
#define HC 64       // heads * channels
#define LRELU 0.2f

__device__ __forceinline__ float lrelu(float x) { return fmaxf(x, LRELU * x); }
__device__ __forceinline__ float eluf(float x) { return x > 0.f ? x : (expf(x) - 1.f); }

// ---------------------------------------------------------------------------
// K0: detect edge_index dtype (int64 vs int32) + precompute effective attention
//     vectors weff[k][0..3] = [Wsrc@att_src(h0), Wsrc@att_src(h1),
//                              Wdst@att_dst(h0), Wdst@att_dst(h1)]
// ---------------------------------------------------------------------------
__global__ void prep_kernel(const void* ei, const float* __restrict__ Wsrc,
                            const float* __restrict__ Wdst,
                            const float* __restrict__ att_src,
                            const float* __restrict__ att_dst,
                            float* __restrict__ weff, int* __restrict__ flag) {
    int t = threadIdx.x;
    if (t == 0) {
        // int64 little-endian: odd 32-bit words are high words == 0 (values < 2^31).
        // int32: odd words are random node indices; P(all 32 are zero) ~ 0.
        const unsigned* u = (const unsigned*)ei;
        int all0 = 1;
        for (int j = 1; j < 64; j += 2) all0 &= (u[j] == 0u);
        *flag = all0;
    }
    if (t < DD) {
        float s0 = 0.f, s1 = 0.f, d0 = 0.f, d1 = 0.f;
        for (int c = 0; c < 32; ++c) {
            s0 += Wsrc[t * HC + c]      * att_src[c];
            s1 += Wsrc[t * HC + 32 + c] * att_src[32 + c];
            d0 += Wdst[t * HC + c]      * att_dst[c];
            d1 += Wdst[t * HC + 32 + c] * att_dst[32 + c];
        }
        weff[t * 4 + 0] = s0; weff[t * 4 + 1] = s1;
        weff[t * 4 + 2] = d0; weff[t * 4 + 3] = d1;
    }
}

// ---------------------------------------------------------------------------
// K1: convert edge_index to int32 + histogram degrees for both groupings
// ---------------------------------------------------------------------------
__global__ void convert_hist_kernel(const void* ei, int E, const int* __restrict__ flag,
                                    int* __restrict__ src32, int* __restrict__ dst32,
                                    int* __restrict__ hist0, int* __restrict__ hist1) {
    int i = blockIdx.x * blockDim.x + threadIdx.x;
    if (i >= E) return;
    int s, d;
    if (*flag) {
        const long long* p = (const long long*)ei;
        s = (int)p[i]; d = (int)p[E + i];
    } else {
        const int* p = (const int*)ei;
        s = p[i]; d = p[E + i];
    }
    src32[i] = s; dst32[i] = d;
    atomicAdd(&hist0[d], 1);   // group by dst  (t_rep pass)
    atomicAdd(&hist1[s], 1);   // group by src  (h_rep pass)
}

// ---------------------------------------------------------------------------
// K2: exclusive prefix scan of both histograms (one block each)
// ---------------------------------------------------------------------------
__global__ void scan_kernel(const int* __restrict__ hist0, const int* __restrict__ hist1,
                            int* __restrict__ off0, int* __restrict__ off1, int n) {
    const int* hist = blockIdx.x ? hist1 : hist0;
    int* off        = blockIdx.x ? off1  : off0;
    __shared__ int part[1024];
    int t = threadIdx.x;
    int CH = (n + 1023) / 1024;
    int b = t * CH, e = min(b + CH, n);
    int s = 0;
    for (int i = b; i < e; ++i) s += hist[i];
    part[t] = s;
    __syncthreads();
    for (int d2 = 1; d2 < 1024; d2 <<= 1) {
        int v = (t >= d2) ? part[t - d2] : 0;
        __syncthreads();
        part[t] += v;
        __syncthreads();
    }
    int run = part[t] - s;             // exclusive prefix at chunk start
    for (int i = b; i < e; ++i) { off[i] = run; run += hist[i]; }
    if (t == 1023) off[n] = part[1023];
}

// ---------------------------------------------------------------------------
// K3: scatter edges into CSR lists (stores the *other* endpoint)
// ---------------------------------------------------------------------------
__global__ void scatter_kernel(const int* __restrict__ src32, const int* __restrict__ dst32,
                               int E, const int* __restrict__ off0, const int* __restrict__ off1,
                               int* __restrict__ cnt0, int* __restrict__ cnt1,
                               int* __restrict__ csr0, int* __restrict__ csr1) {
    int i = blockIdx.x * blockDim.x + threadIdx.x;
    if (i >= E) return;
    int s = src32[i], d = dst32[i];
    int p0 = off0[d] + atomicAdd(&cnt0[d], 1);
    csr0[p0] = s;                      // per t-node: list of h-side sources
    int p1 = off1[s] + atomicAdd(&cnt1[s], 1);
    csr1[p1] = d;                      // per h-node: list of t-side sources
}

// ---------------------------------------------------------------------------
// K4: fused elu + GEMM  [N,256] @ [256, 64+4]  for both sides.
//     Main 64 cols -> xs; 4 extra cols (weff) -> a_s (2 heads), a_d (2 heads).
//     Tile: 64 rows x 64 k-chunk, 256 threads, 16 accumulators/thread.
// ---------------------------------------------------------------------------
__global__ __launch_bounds__(256) void gemm_proj_kernel(
    const float* __restrict__ Xh, const float* __restrict__ Xt,
    const float* __restrict__ Wsrc, const float* __restrict__ weff,
    float* __restrict__ xs_h, float* __restrict__ xs_t,
    float* __restrict__ as_h, float* __restrict__ ad_h,
    float* __restrict__ as_t, float* __restrict__ ad_t, int nrows) {

    const float* X = blockIdx.y ? Xt : Xh;
    float* xs  = blockIdx.y ? xs_t : xs_h;
    float* as_ = blockIdx.y ? as_t : as_h;
    float* ad_ = blockIdx.y ? ad_t : ad_h;

    __shared__ float Xc[64][68];   // +4 pad: keeps float4 alignment, breaks bank stride
    __shared__ float Wc[64][64];
    __shared__ float Wec[64][4];

    int tid = threadIdx.x;
    int row0 = blockIdx.x * 64;
    int c = tid & 63, rg = tid >> 6;

    float acc[16];
#pragma unroll
    for (int i = 0; i < 16; ++i) acc[i] = 0.f;
    float eacc = 0.f;

    for (int kc = 0; kc < 4; ++kc) {
        int r = tid >> 2, cq = tid & 3;
        int row = row0 + r;
#pragma unroll
        for (int q = 0; q < 4; ++q) {
            float4 v;
            if (row < nrows) {
                v = *(const float4*)(X + (size_t)row * DD + kc * 64 + cq * 16 + q * 4);
                v.x = eluf(v.x); v.y = eluf(v.y); v.z = eluf(v.z); v.w = eluf(v.w);
            } else {
                v = make_float4(0.f, 0.f, 0.f, 0.f);
            }
            *(float4*)&Xc[r][cq * 16 + q * 4] = v;
        }
#pragma unroll
        for (int q = 0; q < 4; ++q) {
            *(float4*)&Wc[r][cq * 16 + q * 4] =
                *(const float4*)(Wsrc + (size_t)(kc * 64 + r) * HC + cq * 16 + q * 4);
        }
        Wec[tid >> 2][tid & 3] = weff[(kc * 64 + (tid >> 2)) * 4 + (tid & 3)];
        __syncthreads();

#pragma unroll 4
        for (int kq = 0; kq < 16; ++kq) {
            float w0 = Wc[kq * 4 + 0][c], w1 = Wc[kq * 4 + 1][c];
            float w2 = Wc[kq * 4 + 2][c], w3 = Wc[kq * 4 + 3][c];
#pragma unroll
            for (int i = 0; i < 16; ++i) {
                float4 xv = *(const float4*)&Xc[rg * 16 + i][kq * 4];
                acc[i] = fmaf(xv.x, w0, acc[i]);
                acc[i] = fmaf(xv.y, w1, acc[i]);
                acc[i] = fmaf(xv.z, w2, acc[i]);
                acc[i] = fmaf(xv.w, w3, acc[i]);
            }
        }
        {   // extra columns: a_s / a_d effective dots
            int rr = tid & 63, cp = tid >> 6;
#pragma unroll 4
            for (int kq = 0; kq < 16; ++kq) {
                float4 xv = *(const float4*)&Xc[rr][kq * 4];
                eacc = fmaf(xv.x, Wec[kq * 4 + 0][cp], eacc);
                eacc = fmaf(xv.y, Wec[kq * 4 + 1][cp], eacc);
                eacc = fmaf(xv.z, Wec[kq * 4 + 2][cp], eacc);
                eacc = fmaf(xv.w, Wec[kq * 4 + 3][cp], eacc);
            }
        }
        __syncthreads();
    }

#pragma unroll
    for (int i = 0; i < 16; ++i) {
        int row = row0 + rg * 16 + i;
        if (row < nrows) xs[(size_t)row * HC + c] = acc[i];
    }
    {
        int rr = tid & 63, cp = tid >> 6;
        int row = row0 + rr;
        if (row < nrows) {
            if (cp < 2) as_[row * 2 + cp] = eacc;
            else        ad_[row * 2 + (cp - 2)] = eacc;
        }
    }
}

// ---------------------------------------------------------------------------
// K5: CSR attention. One wave (64 lanes = 2 heads x 32 channels) per dst node.
//     No atomics; softmax without max-subtraction (|logit| <~ 14, exp safe);
//     self-loop added implicitly; bias + normalize fused.
// ---------------------------------------------------------------------------
__global__ __launch_bounds__(256) void gat_csr_kernel(
    const int* __restrict__ off0, const int* __restrict__ csr0,
    const int* __restrict__ off1, const int* __restrict__ csr1,
    const float* __restrict__ xs_h, const float* __restrict__ xs_t,
    const float* __restrict__ as_h, const float* __restrict__ ad_h,
    const float* __restrict__ as_t, const float* __restrict__ ad_t,
    const float* __restrict__ bias, float* __restrict__ out, int N) {

    int lane = threadIdx.x & 63;
    int wid = blockIdx.x * 4 + (threadIdx.x >> 6);
    if (wid >= 2 * N) return;
    int p = (wid >= N) ? 1 : 0;
    int n = wid - p * N;

    const int *off, *csr;
    const float *xs, *as_, *ad_;
    float* o;
    if (p == 0) {   // h_rep: dst = edge_index[0], sources on t side
        off = off1; csr = csr1; xs = xs_t; as_ = as_t; ad_ = ad_h; o = out;
    } else {        // t_rep: dst = edge_index[1], sources on h side
        off = off0; csr = csr0; xs = xs_h; as_ = as_h; ad_ = ad_t; o = out + (size_t)N * HC;
    }

    int h = lane >> 5;
    float adn = ad_[n * 2 + h];
    int beg = off[n], end = off[n + 1];

    float dn = 0.f, acc = 0.f;
    {   // self loop
        float l = lrelu(as_[n * 2 + h] + adn);
        float ex = __expf(l);
        dn += ex;
        acc += ex * xs[(size_t)n * HC + lane];
    }
    for (int e = beg; e < end; ++e) {
        int s = csr[e];
        float l = lrelu(as_[s * 2 + h] + adn);
        float ex = __expf(l);
        dn += ex;
        acc = fmaf(ex, xs[(size_t)s * HC + lane], acc);
    }
    o[(size_t)n * HC + lane] = acc / (dn + 1e-16f) + bias[lane];
}

// ---------------------------------------------------------------------------
extern "C" void kernel_launch(void* const* d_in, const int* in_sizes, int n_in,
                              void* d_out, int out_size, void* d_ws, size_t ws_size,
                              hipStream_t stream) {
    const float* h_x     = (const float*)d_in[0];
    const float* t_x     = (const float*)d_in[1];
    const void*  ei      = d_in[2];
    const float* Wsrc    = (const float*)d_in[3];
    const float* Wdst    = (const float*)d_in[4];
    const float* att_src = (const float*)d_in[5];
    const float* att_dst = (const float*)d_in[6];
    const float* bias    = (const float*)d_in[7];

    const int N = in_sizes[0] / DD;
    const int E = in_sizes[2] / 2;
    float* out = (float*)d_out;

    char* w = (char*)d_ws;
    auto alloc = [&](size_t bytes) -> char* {
        char* p = w;
        w += (bytes + 255) & ~(size_t)255;
        return p;
    };
    int*   src32 = (int*)alloc((size_t)E * 4);
    int*   dst32 = (int*)alloc((size_t)E * 4);
    int*   hist0 = (int*)alloc((size_t)N * 4);   // ---- zeroed region start
    int*   hist1 = (int*)alloc((size_t)N * 4);
    int*   cnt0  = (int*)alloc((size_t)N * 4);
    int*   cnt1  = (int*)alloc((size_t)N * 4);   // ---- zeroed region end
    int*   off0  = (int*)alloc((size_t)(N + 1) * 4);
    int*   off1  = (int*)alloc((size_t)(N + 1) * 4);
    int*   csr0  = (int*)alloc((size_t)E * 4);
    int*   csr1  = (int*)alloc((size_t)E * 4);
    float* xs_h  = (float*)alloc((size_t)N * HC * 4);
    float* xs_t  = (float*)alloc((size_t)N * HC * 4);
    float* as_h  = (float*)alloc((size_t)N * 2 * 4);
    float* ad_h  = (float*)alloc((size_t)N * 2 * 4);
    float* as_t  = (float*)alloc((size_t)N * 2 * 4);
    float* ad_t  = (float*)alloc((size_t)N * 2 * 4);
    float* weff  = (float*)alloc((size_t)DD * 4 * 4);
    int*   flag  = (int*)alloc(256);

    // zero hist0..cnt1 (ws is re-poisoned 0xAA before every timed launch)
    hipMemsetAsync(hist0, 0, (size_t)((char*)off0 - (char*)hist0), stream);

    prep_kernel<<<1, 256, 0, stream>>>(ei, Wsrc, Wdst, att_src, att_dst, weff, flag);

    int gE = (E + 255) / 256;
    convert_hist_kernel<<<gE, 256, 0, stream>>>(ei, E, flag, src32, dst32, hist0, hist1);

    scan_kernel<<<2, 1024, 0, stream>>>(hist0, hist1, off0, off1, N);

    scatter_kernel<<<gE, 256, 0, stream>>>(src32, dst32, E, off0, off1,
                                           cnt0, cnt1, csr0, csr1);

    dim3 gg((N + 63) / 64, 2);
    gemm_proj_kernel<<<gg, 256, 0, stream>>>(h_x, t_x, Wsrc, weff,
                                             xs_h, xs_t, as_h, ad_h, as_t, ad_t, N);

    int gA = (2 * N + 3) / 4;
    gat_csr_kernel<<<gA, 256, 0, stream>>>(off0, csr0, off1, csr1,
                                           xs_h, xs_t, as_h, ad_h, as_t, ad_t,
                                           bias, out, N);
}

// Round 3
// 613.473 us; speedup vs baseline: 1.1555x; 1.1555x over previous
//
#include <hip/hip_runtime.h>
#include <hip/hip_bf16.h>
#include <cstdint>

#define DD 256      // input dim
#define HC 64       // heads * channels
#define LRELU 0.2f

__device__ __forceinline__ float lrelu(float x) { return fmaxf(x, LRELU * x); }
__device__ __forceinline__ float eluf(float x) { return x > 0.f ? x : (expf(x) - 1.f); }

// ---------------------------------------------------------------------------
// K0: detect edge_index dtype (int64 vs int32) + precompute effective attention
//     vectors weff[k][0..3] = [Wsrc@att_src(h0), Wsrc@att_src(h1),
//                              Wdst@att_dst(h0), Wdst@att_dst(h1)]
// ---------------------------------------------------------------------------
__global__ void prep_kernel(const void* ei, const float* __restrict__ Wsrc,
                            const float* __restrict__ Wdst,
                            const float* __restrict__ att_src,
                            const float* __restrict__ att_dst,
                            float* __restrict__ weff, int* __restrict__ flag) {
    int t = threadIdx.x;
    if (t == 0) {
        // int64 little-endian: odd 32-bit words are high words == 0 (values < 2^31).
        const unsigned* u = (const unsigned*)ei;
        int all0 = 1;
        for (int j = 1; j < 64; j += 2) all0 &= (u[j] == 0u);
        *flag = all0;
    }
    if (t < DD) {
        float s0 = 0.f, s1 = 0.f, d0 = 0.f, d1 = 0.f;
        for (int c = 0; c < 32; ++c) {
            s0 += Wsrc[t * HC + c]      * att_src[c];
            s1 += Wsrc[t * HC + 32 + c] * att_src[32 + c];
            d0 += Wdst[t * HC + c]      * att_dst[c];
            d1 += Wdst[t * HC + 32 + c] * att_dst[32 + c];
        }
        weff[t * 4 + 0] = s0; weff[t * 4 + 1] = s1;
        weff[t * 4 + 2] = d0; weff[t * 4 + 3] = d1;
    }
}

// ---------------------------------------------------------------------------
// K1: convert edge_index to int32 + histogram degrees for both groupings
// ---------------------------------------------------------------------------
__global__ void convert_hist_kernel(const void* ei, int E, const int* __restrict__ flag,
                                    int* __restrict__ src32, int* __restrict__ dst32,
                                    int* __restrict__ hist0, int* __restrict__ hist1) {
    int i = blockIdx.x * blockDim.x + threadIdx.x;
    if (i >= E) return;
    int s, d;
    if (*flag) {
        const long long* p = (const long long*)ei;
        s = (int)p[i]; d = (int)p[E + i];
    } else {
        const int* p = (const int*)ei;
        s = p[i]; d = p[E + i];
    }
    src32[i] = s; dst32[i] = d;
    atomicAdd(&hist0[d], 1);   // group by dst  (t_rep pass)
    atomicAdd(&hist1[s], 1);   // group by src  (h_rep pass)
}

// ---------------------------------------------------------------------------
// K2: exclusive prefix scan of both histograms (one block each)
// ---------------------------------------------------------------------------
__global__ void scan_kernel(const int* __restrict__ hist0, const int* __restrict__ hist1,
                            int* __restrict__ off0, int* __restrict__ off1, int n) {
    const int* hist = blockIdx.x ? hist1 : hist0;
    int* off        = blockIdx.x ? off1  : off0;
    __shared__ int part[1024];
    int t = threadIdx.x;
    int CH = (n + 1023) / 1024;
    int b = t * CH, e = min(b + CH, n);
    int s = 0;
    for (int i = b; i < e; ++i) s += hist[i];
    part[t] = s;
    __syncthreads();
    for (int d2 = 1; d2 < 1024; d2 <<= 1) {
        int v = (t >= d2) ? part[t - d2] : 0;
        __syncthreads();
        part[t] += v;
        __syncthreads();
    }
    int run = part[t] - s;             // exclusive prefix at chunk start
    for (int i = b; i < e; ++i) { off[i] = run; run += hist[i]; }
    if (t == 1023) off[n] = part[1023];
}

// ---------------------------------------------------------------------------
// K3: scatter edges into CSR lists (stores the *other* endpoint)
// ---------------------------------------------------------------------------
__global__ void scatter_kernel(const int* __restrict__ src32, const int* __restrict__ dst32,
                               int E, const int* __restrict__ off0, const int* __restrict__ off1,
                               int* __restrict__ cnt0, int* __restrict__ cnt1,
                               int* __restrict__ csr0, int* __restrict__ csr1) {
    int i = blockIdx.x * blockDim.x + threadIdx.x;
    if (i >= E) return;
    int s = src32[i], d = dst32[i];
    int p0 = off0[d] + atomicAdd(&cnt0[d], 1);
    csr0[p0] = s;                      // per t-node: list of h-side sources
    int p1 = off1[s] + atomicAdd(&cnt1[s], 1);
    csr1[p1] = d;                      // per h-node: list of t-side sources
}

// ---------------------------------------------------------------------------
// K4: fused elu + GEMM  [N,256] @ [256, 64+4]  for both sides.
//     Tile 128 rows x 64 cols, BK=32, 256 threads.
//     Per thread: 8 rows x 4 cols register tile (1.5 LDS bytes/FMA)
//     + 2 eff-column accumulators (attention scalars a_s / a_d).
//     Row interleave g+i*16 keeps per-instruction LDS banks distinct.
// ---------------------------------------------------------------------------
__global__ __launch_bounds__(256) void gemm_proj_kernel(
    const float* __restrict__ Xh, const float* __restrict__ Xt,
    const float* __restrict__ Wsrc, const float* __restrict__ weff,
    float* __restrict__ xs_h, float* __restrict__ xs_t,
    float* __restrict__ as_h, float* __restrict__ ad_h,
    float* __restrict__ as_t, float* __restrict__ ad_t, int nrows) {

    const float* X = blockIdx.y ? Xt : Xh;
    float* xs  = blockIdx.y ? xs_t : xs_h;
    float* as_ = blockIdx.y ? as_t : as_h;
    float* ad_ = blockIdx.y ? ad_t : ad_h;

    __shared__ float Xc[128][36];   // rows x k (pad 36: bank spread, 16B aligned)
    __shared__ float Wc[32][72];    // k x cols (pad 72)
    __shared__ float Wec[4][40];    // eff col x k

    const int tid  = threadIdx.x;
    const int row0 = blockIdx.x * 128;

    const int g  = tid >> 4;         // 0..15 row group (rows g + i*16)
    const int c0 = (tid & 15) * 4;   // col base
    const int er = tid >> 1;         // eff row (0..127)
    const int ec = (tid & 1) * 2;    // eff col base: 0 -> a_s pair, 2 -> a_d pair

    float acc[8][4];
#pragma unroll
    for (int i = 0; i < 8; ++i)
#pragma unroll
        for (int j = 0; j < 4; ++j) acc[i][j] = 0.f;
    float ea0 = 0.f, ea1 = 0.f;

    for (int kc = 0; kc < 8; ++kc) {
        // stage X tile (elu applied)
        {
            int r = tid >> 3, cq = tid & 7;
#pragma unroll
            for (int rr = 0; rr < 4; ++rr) {
                int row = row0 + r + rr * 32;
                float4 v = make_float4(0.f, 0.f, 0.f, 0.f);
                if (row < nrows) {
                    v = *(const float4*)(X + (size_t)row * DD + kc * 32 + cq * 4);
                    v.x = eluf(v.x); v.y = eluf(v.y); v.z = eluf(v.z); v.w = eluf(v.w);
                }
                *(float4*)&Xc[r + rr * 32][cq * 4] = v;
            }
        }
        // stage W tile (k-major) + eff vectors
        {
#pragma unroll
            for (int q = 0; q < 2; ++q) {
                int idx = tid + q * 256;            // 0..511
                int k = idx >> 4, cf = idx & 15;
                *(float4*)&Wc[k][cf * 4] =
                    *(const float4*)(Wsrc + (size_t)(kc * 32 + k) * HC + cf * 4);
            }
            if (tid < 128) {
                int k = tid >> 2, j = tid & 3;
                Wec[j][k] = weff[(kc * 32 + k) * 4 + j];
            }
        }
        __syncthreads();

        // main 8x4 register tile
#pragma unroll
        for (int kq = 0; kq < 8; ++kq) {
            float4 w0 = *(const float4*)&Wc[kq * 4 + 0][c0];
            float4 w1 = *(const float4*)&Wc[kq * 4 + 1][c0];
            float4 w2 = *(const float4*)&Wc[kq * 4 + 2][c0];
            float4 w3 = *(const float4*)&Wc[kq * 4 + 3][c0];
#pragma unroll
            for (int i = 0; i < 8; ++i) {
                float4 xv = *(const float4*)&Xc[g + i * 16][kq * 4];
                acc[i][0] = fmaf(xv.x, w0.x, acc[i][0]);
                acc[i][1] = fmaf(xv.x, w0.y, acc[i][1]);
                acc[i][2] = fmaf(xv.x, w0.z, acc[i][2]);
                acc[i][3] = fmaf(xv.x, w0.w, acc[i][3]);
                acc[i][0] = fmaf(xv.y, w1.x, acc[i][0]);
                acc[i][1] = fmaf(xv.y, w1.y, acc[i][1]);
                acc[i][2] = fmaf(xv.y, w1.z, acc[i][2]);
                acc[i][3] = fmaf(xv.y, w1.w, acc[i][3]);
                acc[i][0] = fmaf(xv.z, w2.x, acc[i][0]);
                acc[i][1] = fmaf(xv.z, w2.y, acc[i][1]);
                acc[i][2] = fmaf(xv.z, w2.z, acc[i][2]);
                acc[i][3] = fmaf(xv.z, w2.w, acc[i][3]);
                acc[i][0] = fmaf(xv.w, w3.x, acc[i][0]);
                acc[i][1] = fmaf(xv.w, w3.y, acc[i][1]);
                acc[i][2] = fmaf(xv.w, w3.z, acc[i][2]);
                acc[i][3] = fmaf(xv.w, w3.w, acc[i][3]);
            }
        }
        // eff columns (a_s / a_d)
#pragma unroll
        for (int kq = 0; kq < 8; ++kq) {
            float4 xv = *(const float4*)&Xc[er][kq * 4];
            float4 u0 = *(const float4*)&Wec[ec][kq * 4];
            float4 u1 = *(const float4*)&Wec[ec + 1][kq * 4];
            ea0 = fmaf(xv.x, u0.x, ea0); ea0 = fmaf(xv.y, u0.y, ea0);
            ea0 = fmaf(xv.z, u0.z, ea0); ea0 = fmaf(xv.w, u0.w, ea0);
            ea1 = fmaf(xv.x, u1.x, ea1); ea1 = fmaf(xv.y, u1.y, ea1);
            ea1 = fmaf(xv.z, u1.z, ea1); ea1 = fmaf(xv.w, u1.w, ea1);
        }
        __syncthreads();
    }

#pragma unroll
    for (int i = 0; i < 8; ++i) {
        int row = row0 + g + i * 16;
        if (row < nrows)
            *(float4*)(xs + (size_t)row * HC + c0) =
                make_float4(acc[i][0], acc[i][1], acc[i][2], acc[i][3]);
    }
    {
        int row = row0 + er;
        if (row < nrows) {
            if (ec == 0) { as_[row * 2 + 0] = ea0; as_[row * 2 + 1] = ea1; }
            else         { ad_[row * 2 + 0] = ea0; ad_[row * 2 + 1] = ea1; }
        }
    }
}

// ---------------------------------------------------------------------------
// K5: CSR attention. One wave (64 lanes = 2 heads x 32 channels) per dst node.
//     Unroll-4 over edges with int4 index loads: 4 independent gathers in
//     flight per iteration (latency-bound -> BW-bound).
// ---------------------------------------------------------------------------
__global__ __launch_bounds__(256) void gat_csr_kernel(
    const int* __restrict__ off0, const int* __restrict__ csr0,
    const int* __restrict__ off1, const int* __restrict__ csr1,
    const float* __restrict__ xs_h, const float* __restrict__ xs_t,
    const float* __restrict__ as_h, const float* __restrict__ ad_h,
    const float* __restrict__ as_t, const float* __restrict__ ad_t,
    const float* __restrict__ bias, float* __restrict__ out, int N) {

    int lane = threadIdx.x & 63;
    int wid = blockIdx.x * 4 + (threadIdx.x >> 6);
    if (wid >= 2 * N) return;
    int p = (wid >= N) ? 1 : 0;
    int n = wid - p * N;

    const int *off, *csr;
    const float *xs, *as_, *ad_;
    float* o;
    if (p == 0) {   // h_rep: dst = edge_index[0], sources on t side
        off = off1; csr = csr1; xs = xs_t; as_ = as_t; ad_ = ad_h; o = out;
    } else {        // t_rep: dst = edge_index[1], sources on h side
        off = off0; csr = csr0; xs = xs_h; as_ = as_h; ad_ = ad_t; o = out + (size_t)N * HC;
    }

    int h = lane >> 5;
    float adn = ad_[n * 2 + h];
    int beg = off[n], end = off[n + 1];
    const float* xsl = xs + lane;

    float dn = 0.f, acc = 0.f;
    {   // self loop
        float l = lrelu(as_[n * 2 + h] + adn);
        float ex = __expf(l);
        dn += ex;
        acc += ex * xsl[(size_t)n * HC];
    }

    int e = beg;
    int npre = min(end - e, (4 - (e & 3)) & 3);   // align to int4
    for (int i = 0; i < npre; ++i, ++e) {
        int s = csr[e];
        float l = lrelu(as_[s * 2 + h] + adn);
        float ex = __expf(l);
        dn += ex;
        acc = fmaf(ex, xsl[(size_t)s * HC], acc);
    }
    for (; e + 4 <= end; e += 4) {
        int4 s4 = *(const int4*)(csr + e);
        float A0 = as_[s4.x * 2 + h], A1 = as_[s4.y * 2 + h];
        float A2 = as_[s4.z * 2 + h], A3 = as_[s4.w * 2 + h];
        float X0 = xsl[(size_t)s4.x * HC], X1 = xsl[(size_t)s4.y * HC];
        float X2 = xsl[(size_t)s4.z * HC], X3 = xsl[(size_t)s4.w * HC];
        float e0 = __expf(lrelu(A0 + adn));
        float e1 = __expf(lrelu(A1 + adn));
        float e2 = __expf(lrelu(A2 + adn));
        float e3 = __expf(lrelu(A3 + adn));
        dn += e0; acc = fmaf(e0, X0, acc);
        dn += e1; acc = fmaf(e1, X1, acc);
        dn += e2; acc = fmaf(e2, X2, acc);
        dn += e3; acc = fmaf(e3, X3, acc);
    }
    for (; e < end; ++e) {
        int s = csr[e];
        float l = lrelu(as_[s * 2 + h] + adn);
        float ex = __expf(l);
        dn += ex;
        acc = fmaf(ex, xsl[(size_t)s * HC], acc);
    }
    o[(size_t)n * HC + lane] = acc / (dn + 1e-16f) + bias[lane];
}

// ---------------------------------------------------------------------------
extern "C" void kernel_launch(void* const* d_in, const int* in_sizes, int n_in,
                              void* d_out, int out_size, void* d_ws, size_t ws_size,
                              hipStream_t stream) {
    const float* h_x     = (const float*)d_in[0];
    const float* t_x     = (const float*)d_in[1];
    const void*  ei      = d_in[2];
    const float* Wsrc    = (const float*)d_in[3];
    const float* Wdst    = (const float*)d_in[4];
    const float* att_src = (const float*)d_in[5];
    const float* att_dst = (const float*)d_in[6];
    const float* bias    = (const float*)d_in[7];

    const int N = in_sizes[0] / DD;
    const int E = in_sizes[2] / 2;
    float* out = (float*)d_out;

    char* w = (char*)d_ws;
    auto alloc = [&](size_t bytes) -> char* {
        char* p = w;
        w += (bytes + 255) & ~(size_t)255;
        return p;
    };
    int*   src32 = (int*)alloc((size_t)E * 4);
    int*   dst32 = (int*)alloc((size_t)E * 4);
    int*   hist0 = (int*)alloc((size_t)N * 4);   // ---- zeroed region start
    int*   hist1 = (int*)alloc((size_t)N * 4);
    int*   cnt0  = (int*)alloc((size_t)N * 4);
    int*   cnt1  = (int*)alloc((size_t)N * 4);   // ---- zeroed region end
    int*   off0  = (int*)alloc((size_t)(N + 1) * 4);
    int*   off1  = (int*)alloc((size_t)(N + 1) * 4);
    int*   csr0  = (int*)alloc((size_t)E * 4);
    int*   csr1  = (int*)alloc((size_t)E * 4);
    float* xs_h  = (float*)alloc((size_t)N * HC * 4);
    float* xs_t  = (float*)alloc((size_t)N * HC * 4);
    float* as_h  = (float*)alloc((size_t)N * 2 * 4);
    float* ad_h  = (float*)alloc((size_t)N * 2 * 4);
    float* as_t  = (float*)alloc((size_t)N * 2 * 4);
    float* ad_t  = (float*)alloc((size_t)N * 2 * 4);
    float* weff  = (float*)alloc((size_t)DD * 4 * 4);
    int*   flag  = (int*)alloc(256);

    // zero hist0..cnt1 (ws is re-poisoned 0xAA before every timed launch)
    hipMemsetAsync(hist0, 0, (size_t)((char*)off0 - (char*)hist0), stream);

    prep_kernel<<<1, 256, 0, stream>>>(ei, Wsrc, Wdst, att_src, att_dst, weff, flag);

    int gE = (E + 255) / 256;
    convert_hist_kernel<<<gE, 256, 0, stream>>>(ei, E, flag, src32, dst32, hist0, hist1);

    scan_kernel<<<2, 1024, 0, stream>>>(hist0, hist1, off0, off1, N);

    scatter_kernel<<<gE, 256, 0, stream>>>(src32, dst32, E, off0, off1,
                                           cnt0, cnt1, csr0, csr1);

    dim3 gg((N + 127) / 128, 2);
    gemm_proj_kernel<<<gg, 256, 0, stream>>>(h_x, t_x, Wsrc, weff,
                                             xs_h, xs_t, as_h, ad_h, as_t, ad_t, N);

    int gA = (2 * N + 3) / 4;
    gat_csr_kernel<<<gA, 256, 0, stream>>>(off0, csr0, off1, csr1,
                                           xs_h, xs_t, as_h, ad_h, as_t, ad_t,
                                           bias, out, N);
}

// Round 4
// 355.606 us; speedup vs baseline: 1.9934x; 1.7251x over previous
//
#include <hip/hip_runtime.h>
#include <hip/hip_bf16.h>
#include <cstdint>

#define DD 256      // input dim
#define HC 64       // heads * channels
#define LRELU 0.2f
#define SH 6        // bucket shift: 64 nodes per bucket
#define NBMAX 1024  // max buckets (requires N <= 65536; here N = 50000)
#define CAP 3072    // per-bucket LDS sort capacity in edges (avg ~1280, max ~1550)

__device__ __forceinline__ float lrelu(float x) { return fmaxf(x, LRELU * x); }
__device__ __forceinline__ float eluf(float x) { return x > 0.f ? x : (expf(x) - 1.f); }

// ---------------------------------------------------------------------------
// K0: detect edge_index dtype (int64 vs int32) + effective attention vectors
//     weff[k][0..3] = [Wsrc@att_src(h0), Wsrc@att_src(h1),
//                      Wdst@att_dst(h0), Wdst@att_dst(h1)]
// ---------------------------------------------------------------------------
__global__ void prep_kernel(const void* ei, const float* __restrict__ Wsrc,
                            const float* __restrict__ Wdst,
                            const float* __restrict__ att_src,
                            const float* __restrict__ att_dst,
                            float* __restrict__ weff, int* __restrict__ flag) {
    int t = threadIdx.x;
    if (t == 0) {
        // int64 little-endian: odd 32-bit words are high words == 0.
        const unsigned* u = (const unsigned*)ei;
        int all0 = 1;
        for (int j = 1; j < 64; j += 2) all0 &= (u[j] == 0u);
        *flag = all0;
    }
    if (t < DD) {
        float s0 = 0.f, s1 = 0.f, d0 = 0.f, d1 = 0.f;
        for (int c = 0; c < 32; ++c) {
            s0 += Wsrc[t * HC + c]      * att_src[c];
            s1 += Wsrc[t * HC + 32 + c] * att_src[32 + c];
            d0 += Wdst[t * HC + c]      * att_dst[c];
            d1 += Wdst[t * HC + 32 + c] * att_dst[32 + c];
        }
        weff[t * 4 + 0] = s0; weff[t * 4 + 1] = s1;
        weff[t * 4 + 2] = d0; weff[t * 4 + 3] = d1;
    }
}

// ---------------------------------------------------------------------------
// K1: bucket histogram for both groupings (LDS-staged; ~200K merge atomics)
//     grouping 0: key = dst (t_rep pass). grouping 1: key = src (h_rep pass).
// ---------------------------------------------------------------------------
__global__ __launch_bounds__(256) void hist_kernel(const void* ei, int E, int NB,
                                                   const int* __restrict__ flag,
                                                   int* __restrict__ bcnt) {
    __shared__ int lc[2 * NBMAX];
    for (int t = threadIdx.x; t < 2 * NB; t += 256) lc[t] = 0;
    __syncthreads();
    const bool f64 = (*flag != 0);
    int stride = gridDim.x * 256;
    for (int i = blockIdx.x * 256 + threadIdx.x; i < E; i += stride) {
        int s, d;
        if (f64) { const long long* p = (const long long*)ei; s = (int)p[i]; d = (int)p[E + i]; }
        else     { const int* p = (const int*)ei;             s = p[i];      d = p[E + i]; }
        atomicAdd(&lc[d >> SH], 1);
        atomicAdd(&lc[NB + (s >> SH)], 1);
    }
    __syncthreads();
    for (int t = threadIdx.x; t < 2 * NB; t += 256)
        if (lc[t]) atomicAdd(&bcnt[t], lc[t]);
}

// ---------------------------------------------------------------------------
// K2: exclusive scan of bucket counts (one block per grouping; NB <= 1024)
//     also initializes the scatter cursors.
// ---------------------------------------------------------------------------
__global__ __launch_bounds__(256) void bscan_kernel(const int* __restrict__ bcnt, int NB,
                                                    int* __restrict__ boff,
                                                    int* __restrict__ cursor) {
    int g = blockIdx.x;
    const int* c = bcnt + g * NB;
    int* off = boff + g * (NB + 1);
    int* cur = cursor + g * NB;
    __shared__ int psum[256];
    int t = threadIdx.x;
    int cpt = (NB + 255) / 256;
    int b0 = t * cpt;
    int s = 0;
    for (int j = 0; j < cpt; ++j) { int b = b0 + j; if (b < NB) s += c[b]; }
    psum[t] = s;
    __syncthreads();
    for (int d2 = 1; d2 < 256; d2 <<= 1) {
        int v = (t >= d2) ? psum[t - d2] : 0;
        __syncthreads();
        psum[t] += v;
        __syncthreads();
    }
    int run = psum[t] - s;
    for (int j = 0; j < cpt; ++j) {
        int b = b0 + j;
        if (b < NB) { off[b] = run; cur[b] = run; run += c[b]; }
    }
    if (t == 255) off[NB] = psum[255];
}

// ---------------------------------------------------------------------------
// K3: binned scatter. Each block: local bucket counts -> reserve one
//     contiguous run per bucket (1 atomic) -> write packed edges into the run.
//     Run writes come from a single CU in a short window -> L2 line-dense,
//     ~1.8x write amp instead of 16x.  packed = (key&63)<<16 | payload.
// ---------------------------------------------------------------------------
__global__ __launch_bounds__(256) void bscatter_kernel(const void* ei, int E, int NB,
                                                       const int* __restrict__ flag,
                                                       int* __restrict__ cursor,
                                                       unsigned* __restrict__ bins0,
                                                       unsigned* __restrict__ bins1) {
    __shared__ int lc[2 * NBMAX];
    for (int t = threadIdx.x; t < 2 * NB; t += 256) lc[t] = 0;
    __syncthreads();
    const bool f64 = (*flag != 0);
    int stride = gridDim.x * 256;
    // pass A: local counts
    for (int i = blockIdx.x * 256 + threadIdx.x; i < E; i += stride) {
        int s, d;
        if (f64) { const long long* p = (const long long*)ei; s = (int)p[i]; d = (int)p[E + i]; }
        else     { const int* p = (const int*)ei;             s = p[i];      d = p[E + i]; }
        atomicAdd(&lc[d >> SH], 1);
        atomicAdd(&lc[NB + (s >> SH)], 1);
    }
    __syncthreads();
    // reserve runs: lc[j] becomes this block's global write cursor for bucket j
    for (int t = threadIdx.x; t < 2 * NB; t += 256) {
        int cvt = lc[t];
        lc[t] = cvt ? atomicAdd(&cursor[t], cvt) : 0;
    }
    __syncthreads();
    // pass C: write packed edges
    for (int i = blockIdx.x * 256 + threadIdx.x; i < E; i += stride) {
        int s, d;
        if (f64) { const long long* p = (const long long*)ei; s = (int)p[i]; d = (int)p[E + i]; }
        else     { const int* p = (const int*)ei;             s = p[i];      d = p[E + i]; }
        int p0 = atomicAdd(&lc[d >> SH], 1);
        bins0[p0] = ((unsigned)(d & 63) << 16) | (unsigned)s;
        int p1 = atomicAdd(&lc[NB + (s >> SH)], 1);
        bins1[p1] = ((unsigned)(s & 63) << 16) | (unsigned)d;
    }
}

// ---------------------------------------------------------------------------
// K4: fused elu + GEMM  [N,256] @ [256, 64+4]  for both sides (unchanged).
// ---------------------------------------------------------------------------
__global__ __launch_bounds__(256) void gemm_proj_kernel(
    const float* __restrict__ Xh, const float* __restrict__ Xt,
    const float* __restrict__ Wsrc, const float* __restrict__ weff,
    float* __restrict__ xs_h, float* __restrict__ xs_t,
    float* __restrict__ as_h, float* __restrict__ ad_h,
    float* __restrict__ as_t, float* __restrict__ ad_t, int nrows) {

    const float* X = blockIdx.y ? Xt : Xh;
    float* xs  = blockIdx.y ? xs_t : xs_h;
    float* as_ = blockIdx.y ? as_t : as_h;
    float* ad_ = blockIdx.y ? ad_t : ad_h;

    __shared__ float Xc[128][36];
    __shared__ float Wc[32][72];
    __shared__ float Wec[4][40];

    const int tid  = threadIdx.x;
    const int row0 = blockIdx.x * 128;

    const int g  = tid >> 4;
    const int c0 = (tid & 15) * 4;
    const int er = tid >> 1;
    const int ec = (tid & 1) * 2;

    float acc[8][4];
#pragma unroll
    for (int i = 0; i < 8; ++i)
#pragma unroll
        for (int j = 0; j < 4; ++j) acc[i][j] = 0.f;
    float ea0 = 0.f, ea1 = 0.f;

    for (int kc = 0; kc < 8; ++kc) {
        {
            int r = tid >> 3, cq = tid & 7;
#pragma unroll
            for (int rr = 0; rr < 4; ++rr) {
                int row = row0 + r + rr * 32;
                float4 v = make_float4(0.f, 0.f, 0.f, 0.f);
                if (row < nrows) {
                    v = *(const float4*)(X + (size_t)row * DD + kc * 32 + cq * 4);
                    v.x = eluf(v.x); v.y = eluf(v.y); v.z = eluf(v.z); v.w = eluf(v.w);
                }
                *(float4*)&Xc[r + rr * 32][cq * 4] = v;
            }
        }
        {
#pragma unroll
            for (int q = 0; q < 2; ++q) {
                int idx = tid + q * 256;
                int k = idx >> 4, cf = idx & 15;
                *(float4*)&Wc[k][cf * 4] =
                    *(const float4*)(Wsrc + (size_t)(kc * 32 + k) * HC + cf * 4);
            }
            if (tid < 128) {
                int k = tid >> 2, j = tid & 3;
                Wec[j][k] = weff[(kc * 32 + k) * 4 + j];
            }
        }
        __syncthreads();

#pragma unroll
        for (int kq = 0; kq < 8; ++kq) {
            float4 w0 = *(const float4*)&Wc[kq * 4 + 0][c0];
            float4 w1 = *(const float4*)&Wc[kq * 4 + 1][c0];
            float4 w2 = *(const float4*)&Wc[kq * 4 + 2][c0];
            float4 w3 = *(const float4*)&Wc[kq * 4 + 3][c0];
#pragma unroll
            for (int i = 0; i < 8; ++i) {
                float4 xv = *(const float4*)&Xc[g + i * 16][kq * 4];
                acc[i][0] = fmaf(xv.x, w0.x, acc[i][0]);
                acc[i][1] = fmaf(xv.x, w0.y, acc[i][1]);
                acc[i][2] = fmaf(xv.x, w0.z, acc[i][2]);
                acc[i][3] = fmaf(xv.x, w0.w, acc[i][3]);
                acc[i][0] = fmaf(xv.y, w1.x, acc[i][0]);
                acc[i][1] = fmaf(xv.y, w1.y, acc[i][1]);
                acc[i][2] = fmaf(xv.y, w1.z, acc[i][2]);
                acc[i][3] = fmaf(xv.y, w1.w, acc[i][3]);
                acc[i][0] = fmaf(xv.z, w2.x, acc[i][0]);
                acc[i][1] = fmaf(xv.z, w2.y, acc[i][1]);
                acc[i][2] = fmaf(xv.z, w2.z, acc[i][2]);
                acc[i][3] = fmaf(xv.z, w2.w, acc[i][3]);
                acc[i][0] = fmaf(xv.w, w3.x, acc[i][0]);
                acc[i][1] = fmaf(xv.w, w3.y, acc[i][1]);
                acc[i][2] = fmaf(xv.w, w3.z, acc[i][2]);
                acc[i][3] = fmaf(xv.w, w3.w, acc[i][3]);
            }
        }
#pragma unroll
        for (int kq = 0; kq < 8; ++kq) {
            float4 xv = *(const float4*)&Xc[er][kq * 4];
            float4 u0 = *(const float4*)&Wec[ec][kq * 4];
            float4 u1 = *(const float4*)&Wec[ec + 1][kq * 4];
            ea0 = fmaf(xv.x, u0.x, ea0); ea0 = fmaf(xv.y, u0.y, ea0);
            ea0 = fmaf(xv.z, u0.z, ea0); ea0 = fmaf(xv.w, u0.w, ea0);
            ea1 = fmaf(xv.x, u1.x, ea1); ea1 = fmaf(xv.y, u1.y, ea1);
            ea1 = fmaf(xv.z, u1.z, ea1); ea1 = fmaf(xv.w, u1.w, ea1);
        }
        __syncthreads();
    }

#pragma unroll
    for (int i = 0; i < 8; ++i) {
        int row = row0 + g + i * 16;
        if (row < nrows)
            *(float4*)(xs + (size_t)row * HC + c0) =
                make_float4(acc[i][0], acc[i][1], acc[i][2], acc[i][3]);
    }
    {
        int row = row0 + er;
        if (row < nrows) {
            if (ec == 0) { as_[row * 2 + 0] = ea0; as_[row * 2 + 1] = ea1; }
            else         { ad_[row * 2 + 0] = ea0; ad_[row * 2 + 1] = ea1; }
        }
    }
}

// ---------------------------------------------------------------------------
// K5: GAT attention, one block per bucket (64 dst nodes), fused in-LDS
//     counting sort of the bucket's packed edges, then 4 waves x 16 nodes
//     with the 4-wide-unrolled gather loop (source ids broadcast from LDS).
// ---------------------------------------------------------------------------
__global__ __launch_bounds__(256) void gat_kernel(
    const unsigned* __restrict__ bins0, const unsigned* __restrict__ bins1,
    const int* __restrict__ boff, int NB,
    const float* __restrict__ xs_h, const float* __restrict__ xs_t,
    const float* __restrict__ as_h, const float* __restrict__ ad_h,
    const float* __restrict__ as_t, const float* __restrict__ ad_t,
    const float* __restrict__ bias, float* __restrict__ out, int N) {

    int g = blockIdx.y;
    int b = blockIdx.x;
    const unsigned* bins = g ? bins1 : bins0;
    const int* off = boff + g * (NB + 1);
    // g==0: key=dst -> t_rep: sources on h side.  g==1: key=src -> h_rep.
    const float *xs, *as_, *ad_;
    float* o;
    if (g == 0) { xs = xs_h; as_ = as_h; ad_ = ad_t; o = out + (size_t)N * HC; }
    else        { xs = xs_t; as_ = as_t; ad_ = ad_h; o = out; }

    __shared__ int cnt64[64];
    __shared__ int lofs[65];
    __shared__ int lpos[64];
    __shared__ unsigned srt[CAP];

    int base = off[b];
    int cnt  = off[b + 1] - base;
    int tid  = threadIdx.x;
    bool fits = (cnt <= CAP);   // block-uniform

    if (fits) {
        if (tid < 64) cnt64[tid] = 0;
        __syncthreads();
        for (int i = tid; i < cnt; i += 256)
            atomicAdd(&cnt64[bins[base + i] >> 16], 1);
        __syncthreads();
        if (tid == 0) {
            int r = 0;
            for (int k = 0; k < 64; ++k) { lofs[k] = r; r += cnt64[k]; }
            lofs[64] = r;
        }
        __syncthreads();
        if (tid < 64) lpos[tid] = lofs[tid];
        __syncthreads();
        for (int i = tid; i < cnt; i += 256) {
            unsigned v = bins[base + i];
            int p = atomicAdd(&lpos[v >> 16], 1);
            srt[p] = v & 0xffffu;
        }
        __syncthreads();
    }

    int wave = tid >> 6, lane = tid & 63, h = lane >> 5;
    const float* xsl = xs + lane;
    int node0 = b << SH;

    for (int q = 0; q < 16; ++q) {
        int nl = wave * 16 + q;
        int n  = node0 + nl;
        if (n >= N) break;
        float adn = ad_[n * 2 + h];
        float dn = 0.f, acc = 0.f;
        {   // self loop
            float ex = __expf(lrelu(as_[n * 2 + h] + adn));
            dn += ex;
            acc += ex * xsl[(size_t)n * HC];
        }
        if (fits) {
            int e = lofs[nl], end = lofs[nl + 1];
            int npre = min(end - e, (4 - (e & 3)) & 3);
            for (int i = 0; i < npre; ++i, ++e) {
                int s = (int)srt[e];
                float ex = __expf(lrelu(as_[s * 2 + h] + adn));
                dn += ex;
                acc = fmaf(ex, xsl[(size_t)s * HC], acc);
            }
            for (; e + 4 <= end; e += 4) {
                uint4 s4 = *(const uint4*)&srt[e];
                float A0 = as_[s4.x * 2 + h], A1 = as_[s4.y * 2 + h];
                float A2 = as_[s4.z * 2 + h], A3 = as_[s4.w * 2 + h];
                float X0 = xsl[(size_t)s4.x * HC], X1 = xsl[(size_t)s4.y * HC];
                float X2 = xsl[(size_t)s4.z * HC], X3 = xsl[(size_t)s4.w * HC];
                float e0 = __expf(lrelu(A0 + adn));
                float e1 = __expf(lrelu(A1 + adn));
                float e2 = __expf(lrelu(A2 + adn));
                float e3 = __expf(lrelu(A3 + adn));
                dn += e0; acc = fmaf(e0, X0, acc);
                dn += e1; acc = fmaf(e1, X1, acc);
                dn += e2; acc = fmaf(e2, X2, acc);
                dn += e3; acc = fmaf(e3, X3, acc);
            }
            for (; e < end; ++e) {
                int s = (int)srt[e];
                float ex = __expf(lrelu(as_[s * 2 + h] + adn));
                dn += ex;
                acc = fmaf(ex, xsl[(size_t)s * HC], acc);
            }
        } else {
            // overflow fallback: scan whole bucket from global (never hit for
            // this input distribution; correctness safety net)
            for (int e = 0; e < cnt; ++e) {
                unsigned v = bins[base + e];
                if ((int)(v >> 16) == nl) {
                    int s = (int)(v & 0xffffu);
                    float ex = __expf(lrelu(as_[s * 2 + h] + adn));
                    dn += ex;
                    acc = fmaf(ex, xsl[(size_t)s * HC], acc);
                }
            }
        }
        o[(size_t)n * HC + lane] = acc / (dn + 1e-16f) + bias[lane];
    }
}

// ---------------------------------------------------------------------------
extern "C" void kernel_launch(void* const* d_in, const int* in_sizes, int n_in,
                              void* d_out, int out_size, void* d_ws, size_t ws_size,
                              hipStream_t stream) {
    const float* h_x     = (const float*)d_in[0];
    const float* t_x     = (const float*)d_in[1];
    const void*  ei      = d_in[2];
    const float* Wsrc    = (const float*)d_in[3];
    const float* Wdst    = (const float*)d_in[4];
    const float* att_src = (const float*)d_in[5];
    const float* att_dst = (const float*)d_in[6];
    const float* bias    = (const float*)d_in[7];

    const int N = in_sizes[0] / DD;
    const int E = in_sizes[2] / 2;
    const int NB = (N + 63) >> SH;      // buckets of 64 nodes
    float* out = (float*)d_out;

    char* w = (char*)d_ws;
    auto alloc = [&](size_t bytes) -> char* {
        char* p = w;
        w += (bytes + 255) & ~(size_t)255;
        return p;
    };
    int*      bcnt   = (int*)alloc((size_t)2 * NB * 4);        // zeroed
    int*      boff   = (int*)alloc((size_t)2 * (NB + 1) * 4);
    int*      cursor = (int*)alloc((size_t)2 * NB * 4);
    unsigned* bins0  = (unsigned*)alloc((size_t)E * 4);
    unsigned* bins1  = (unsigned*)alloc((size_t)E * 4);
    float*    xs_h   = (float*)alloc((size_t)N * HC * 4);
    float*    xs_t   = (float*)alloc((size_t)N * HC * 4);
    float*    as_h   = (float*)alloc((size_t)N * 2 * 4);
    float*    ad_h   = (float*)alloc((size_t)N * 2 * 4);
    float*    as_t   = (float*)alloc((size_t)N * 2 * 4);
    float*    ad_t   = (float*)alloc((size_t)N * 2 * 4);
    float*    weff   = (float*)alloc((size_t)DD * 4 * 4);
    int*      flag   = (int*)alloc(256);

    hipMemsetAsync(bcnt, 0, (size_t)2 * NB * 4, stream);

    prep_kernel<<<1, 256, 0, stream>>>(ei, Wsrc, Wdst, att_src, att_dst, weff, flag);

    hist_kernel<<<256, 256, 0, stream>>>(ei, E, NB, flag, bcnt);

    bscan_kernel<<<2, 256, 0, stream>>>(bcnt, NB, boff, cursor);

    bscatter_kernel<<<128, 256, 0, stream>>>(ei, E, NB, flag, cursor, bins0, bins1);

    dim3 gg((N + 127) / 128, 2);
    gemm_proj_kernel<<<gg, 256, 0, stream>>>(h_x, t_x, Wsrc, weff,
                                             xs_h, xs_t, as_h, ad_h, as_t, ad_t, N);

    dim3 ga(NB, 2);
    gat_kernel<<<ga, 256, 0, stream>>>(bins0, bins1, boff, NB,
                                       xs_h, xs_t, as_h, ad_h, as_t, ad_t,
                                       bias, out, N);
}